// Round 6
// baseline (526.701 us; speedup 1.0000x reference)
//
#include <hip/hip_runtime.h>
#include <hip/hip_bf16.h>
#include <hip/hip_fp16.h>

#define N 8192
#define FIN 256
#define HD 256
#define LEAKY 0.2f

typedef short sh8 __attribute__((ext_vector_type(8)));       // bf16x8 MFMA fragment
typedef _Float16 h8 __attribute__((ext_vector_type(8)));     // f16x8 MFMA fragment
typedef _Float16 h2 __attribute__((ext_vector_type(2)));
typedef float f32x4 __attribute__((ext_vector_type(4)));
typedef int   i32x4 __attribute__((ext_vector_type(4)));
typedef int   i32x2 __attribute__((ext_vector_type(2)));

__device__ __forceinline__ int pack2bf(float a, float b){
  __hip_bfloat162 t = __float22bfloat162_rn(make_float2(a, b));
  union { __hip_bfloat162 h; int i; } u;
  u.h = t;
  return u.i;
}

__device__ __forceinline__ h2 u2h2(unsigned u){ union{unsigned u; h2 h;} c; c.u=u; return c.h; }
__device__ __forceinline__ unsigned h22u(h2 h){ union{unsigned u; h2 h;} c; c.h=h; return c.u; }

// ---------------- K0: W (256x256 f32, [k][c]) -> Wt (bf16, [c][k]) ----------------
__global__ void k_wt(const float* __restrict__ W, __hip_bfloat16* __restrict__ Wt){
  __shared__ float t[16][17];
  int tx = threadIdx.x, ty = threadIdx.y;
  int bx = blockIdx.x*16, by = blockIdx.y*16;
  t[ty][tx] = W[(by+ty)*HD + (bx+tx)];
  __syncthreads();
  Wt[(bx+ty)*FIN + (by+tx)] = __float2bfloat16(t[tx][ty]);
}

// ---------------- K0b: adj (int32 {0,1}, 256 MB) -> interleaved bitmask (8 MB) -----
// word[i][c]: bit b (b<16) = keep(i, c*32+2b), bit 16+b = keep(i, c*32+2b+1).
// Identity diagonal folded in. Coalesced: one contiguous dwordx4 per thread, OR-
// combine across the 8-thread group via shfl_xor.
__global__ __launch_bounds__(256) void k_pack(const int* __restrict__ adj,
                                              unsigned* __restrict__ bits){
  const int g = blockIdx.x*256 + threadIdx.x;   // one dwordx4 chunk per thread
  const i32x4 a = *(const i32x4*)(adj + (size_t)g*4);
  const int sub = g & 7;                        // which 4-of-32 j this thread holds
  unsigned wpart = 0;
  #pragma unroll
  for (int e = 0; e < 4; ++e){
    const int jj = sub*4 + e;                   // j within the 32-chunk
    wpart |= ((unsigned)a[e] & 1u) << ((jj >> 1) + ((jj & 1) << 4));
  }
  wpart |= __shfl_xor(wpart, 1);
  wpart |= __shfl_xor(wpart, 2);
  wpart |= __shfl_xor(wpart, 4);
  if (sub == 0){
    const int t = g >> 3;                       // word index
    const int i = t >> 8;                       // row
    const int c = t & 255;                      // 32-j chunk
    if ((i >> 5) == c){                         // diagonal lands in this word
      const int k = i & 31;
      wpart |= 1u << ((k >> 1) + ((k & 1) << 4));
    }
    bits[t] = wpart;
  }
}

// ---------------- K1: h_t[c][n] (f16) + El/El2 fp32 + Erh/Er2h f16 ------------------
__global__ __launch_bounds__(256, 2) void k_h(
    const float* __restrict__ x, const __hip_bfloat16* __restrict__ Wt,
    const float* __restrict__ a_l, const float* __restrict__ a_r,
    _Float16* __restrict__ ht, float* __restrict__ El, float* __restrict__ El2,
    _Float16* __restrict__ Erh, _Float16* __restrict__ Er2h)
{
  const int lane = threadIdx.x & 63;
  const int w = threadIdx.x >> 6;      // c-group == head
  const int r0 = lane & 15, q = lane >> 4;
  const int c0 = w*64;
  const int n0 = blockIdx.x*16;

  f32x4 acc[4];
  #pragma unroll
  for (int m = 0; m < 4; ++m) acc[m] = (f32x4){0.f, 0.f, 0.f, 0.f};

  for (int kb = 0; kb < 8; ++kb){
    const int k = kb*32 + q*8;
    sh8 af[4];
    #pragma unroll
    for (int m = 0; m < 4; ++m)
      af[m] = *(const sh8*)(Wt + (c0 + m*16 + r0)*FIN + k);
    const float* xp = x + (n0 + r0)*FIN + k;
    f32x4 xl = *(const f32x4*)xp;
    f32x4 xh = *(const f32x4*)(xp + 4);
    union { sh8 s; int i[4]; } bx;
    bx.i[0] = pack2bf(xl[0], xl[1]);
    bx.i[1] = pack2bf(xl[2], xl[3]);
    bx.i[2] = pack2bf(xh[0], xh[1]);
    bx.i[3] = pack2bf(xh[2], xh[3]);
    #pragma unroll
    for (int m = 0; m < 4; ++m)
      acc[m] = __builtin_amdgcn_mfma_f32_16x16x32_bf16(af[m], bx.s, acc[m], 0, 0, 0);
  }

  float pl = 0.f, pr = 0.f;
  #pragma unroll
  for (int m = 0; m < 4; ++m){
    #pragma unroll
    for (int reg = 0; reg < 4; ++reg){
      const int c = c0 + m*16 + q*4 + reg;      // C row = q*4+reg
      const float v = acc[m][reg];
      ht[(size_t)c*N + (n0 + r0)] = (_Float16)v; // C col = r0
      pl += v*a_l[c];
      pr += v*a_r[c];
    }
  }
  pl += __shfl_xor(pl, 16); pl += __shfl_xor(pl, 32);
  pr += __shfl_xor(pr, 16); pr += __shfl_xor(pr, 32);
  if (lane < 16){
    const int n = n0 + r0;
    El  [w*N + n] = __expf(pl);
    El2 [w*N + n] = __expf(LEAKY*pl);
    Erh [w*N + n] = (_Float16)__expf(pr);
    Er2h[w*N + n] = (_Float16)__expf(LEAKY*pr);
  }
}

// ---------------- K2: fused bitmask + masked-softmax partials ----------------------
// grid 1024: b = h*256 + jq*64 + i128 (jq = quarter of j). 4 waves, wave w owns rows
// i128*128 + w*32 + {0,16} + r0.
// NO ht LDS staging: hf fragments loaded global->VGPR (L1/L2-resident; co-resident
// blocks share the same (h,jq) ht slice), double-buffered one 32-j step ahead.
// All 4 waves previously pushed the IDENTICAL 16 KB tile through the LDS pipe (4x
// redundancy) fenced by per-tile barriers -- both eliminated. Only er slices live in
// LDS (broadcast reads, staged once). Zero barriers after the prologue.
__global__ __launch_bounds__(256, 4) void k_attn(
    const unsigned* __restrict__ bits, const _Float16* __restrict__ ht,
    const float* __restrict__ El, const float* __restrict__ El2,
    const _Float16* __restrict__ Erh, const _Float16* __restrict__ Er2h,
    float* __restrict__ part, float* __restrict__ zpart)
{
  __shared__ __align__(16) char smem[8192];     // Erh (4 KB) + Er2h (4 KB) slices
  const int b = blockIdx.x;
  const int h = b >> 8, jq = (b >> 6) & 3, i128 = b & 63;
  const int tid = threadIdx.x;
  const int lane = tid & 63;
  const int w = tid >> 6;
  const int r0 = lane & 15, q = lane >> 4;
  const int ib = i128*128 + w*32;               // this wave's 32-row base
  const int jbase = jq * 2048;

  // stage Erh/Er2h slices (4 KB each) once; wave w moves 1 KB of each
  {
    const _Float16* s1 = Erh  + h*N + jbase + w*512 + lane*8;
    const _Float16* s2 = Er2h + h*N + jbase + w*512 + lane*8;
    __builtin_amdgcn_global_load_lds(
      (const __attribute__((address_space(1))) void*)s1,
      (__attribute__((address_space(3))) void*)(smem + w*1024), 16, 0, 0);
    __builtin_amdgcn_global_load_lds(
      (const __attribute__((address_space(1))) void*)s2,
      (__attribute__((address_space(3))) void*)(smem + 4096 + w*1024), 16, 0, 0);
  }
  const char* erp1 = smem + q*16;
  const char* erp2 = smem + 4096 + q*16;

  const float* el_ = El  + h*N + ib + r0;
  const float* el2_= El2 + h*N + ib + r0;
  h2 elh[2], el2h[2];
  #pragma unroll
  for (int m = 0; m < 2; ++m){
    _Float16 a = (_Float16)el_[m*16];
    _Float16 c = (_Float16)el2_[m*16];
    elh[m]  = (h2){a, a};
    el2h[m] = (h2){c, c};
  }

  // hf global base: feat = d*16 + r0 (row), j = jbase + s*32 + q*8 (16 B per lane)
  const _Float16* hp = ht + (size_t)(h*64 + r0)*N + jbase + q*8;

  // bitmask pointers: row (ib + m*16 + r0), word base jq*64; 1 word per 32-j step
  const unsigned* bp0 = bits + (size_t)(ib + r0)*(N/32) + jq*64;
  const unsigned* bp1 = bp0 + 16*(N/32);
  const int qs = q*4;                            // pair p sits at bits (qs+p, 16+qs+p)

  union { h8 s; int i[4]; } onef;
  {
    int v = (r0 == 0) ? 0x3C003C00 : 0;          // f16 1.0 pair
    onef.i[0]=v; onef.i[1]=v; onef.i[2]=v; onef.i[3]=v;
  }

  f32x4 acc[2][4];
  f32x4 accz[2];
  #pragma unroll
  for (int m = 0; m < 2; ++m){
    accz[m] = (f32x4){0.f,0.f,0.f,0.f};
    #pragma unroll
    for (int d = 0; d < 4; ++d)
      acc[m][d] = (f32x4){0.f,0.f,0.f,0.f};
  }

#define PREF(buf, stp) do { \
    const _Float16* _p = hp + (size_t)(stp)*32; \
    buf[0] = *(const h8*)(_p); \
    buf[1] = *(const h8*)(_p + (size_t)16*N); \
    buf[2] = *(const h8*)(_p + (size_t)32*N); \
    buf[3] = *(const h8*)(_p + (size_t)48*N); \
  } while(0)

#define STEPC(buf, stp, wrd0, wrd1) do { \
    i32x4 er4  = *(const i32x4*)(erp1 + (stp)*64); \
    i32x4 er24 = *(const i32x4*)(erp2 + (stp)*64); \
    _Pragma("unroll") \
    for (int m = 0; m < 2; ++m){ \
      const unsigned wq = ((m) ? (unsigned)(wrd1) : (unsigned)(wrd0)) >> qs; \
      unsigned fu[4]; \
      _Pragma("unroll") \
      for (int p = 0; p < 4; ++p){ \
        const unsigned t32 = (wq >> p) & 0x10001u; \
        const unsigned msk = t32 * 0xFFFFu; \
        h2 w2 = __builtin_elementwise_max(elh[m]  * u2h2((unsigned)er4[p]), \
                                          el2h[m] * u2h2((unsigned)er24[p])); \
        fu[p] = h22u(w2) & msk; \
      } \
      union { h8 s8; unsigned u[4]; } fa; \
      fa.u[0]=fu[0]; fa.u[1]=fu[1]; fa.u[2]=fu[2]; fa.u[3]=fu[3]; \
      __builtin_amdgcn_s_setprio(1); \
      _Pragma("unroll") \
      for (int d = 0; d < 4; ++d) \
        acc[m][d] = __builtin_amdgcn_mfma_f32_16x16x32_f16(fa.s8, buf[d], acc[m][d], 0, 0, 0); \
      accz[m] = __builtin_amdgcn_mfma_f32_16x16x32_f16(fa.s8, onef.s, accz[m], 0, 0, 0); \
      __builtin_amdgcn_s_setprio(0); \
    } \
  } while(0)

  h8 A[4], B[4];
  i32x2 bc0 = *(const i32x2*)bp0;                // bits words for steps 0,1
  i32x2 bc1 = *(const i32x2*)bp1;
  i32x2 bn0, bn1;
  PREF(A, 0);
  __syncthreads();                               // er slices resident (one-time)

  for (int sp = 0; sp < 32; ++sp){               // macro-iter = 2 steps of 32 j
    const int sB = sp*2 + 1;
    const int spn = (sp + 1) & 31;               // wrap: harmless reload at tail
    bn0 = *(const i32x2*)(bp0 + spn*2);
    bn1 = *(const i32x2*)(bp1 + spn*2);
    PREF(B, sB);                                 // next step's hf in flight
    STEPC(A, sp*2, bc0[0], bc1[0]);
    PREF(A, (sB + 1) & 63);                      // step after next (wrap at tail)
    STEPC(B, sB, bc0[1], bc1[1]);
    bc0 = bn0; bc1 = bn1;
  }

  // z partials: col 0 of accz -> lanes with r0==0, row = q*4+reg
  if (r0 == 0){
    #pragma unroll
    for (int m = 0; m < 2; ++m)
      #pragma unroll
      for (int reg = 0; reg < 4; ++reg)
        zpart[(jq*4 + h)*N + ib + m*16 + q*4 + reg] = accz[m][reg];
  }

  // numerator partials: C layout col=r0, row=q*4+reg
  float* pp = part + (size_t)jq*N*HD + h*64 + r0;
  #pragma unroll
  for (int m = 0; m < 2; ++m)
    #pragma unroll
    for (int d = 0; d < 4; ++d)
      #pragma unroll
      for (int reg = 0; reg < 4; ++reg)
        pp[(size_t)(ib + m*16 + q*4 + reg)*HD + d*16] = acc[m][d][reg];
#undef PREF
#undef STEPC
}

// ---------------- K3: combine 4 j-quarter partials, divide, write out --------------
__global__ void k_out(const float* __restrict__ part, const float* __restrict__ zpart,
                      float* __restrict__ out)
{
  const int t4 = (blockIdx.x*256 + threadIdx.x) * 4;   // 4 consecutive c (same head)
  const int i = t4 >> 8;
  const int h = (t4 & 255) >> 6;
  f32x4 a = *(const f32x4*)(part + t4);
  f32x4 bq = *(const f32x4*)(part + (size_t)N*HD + t4);
  f32x4 c = *(const f32x4*)(part + 2*(size_t)N*HD + t4);
  f32x4 d = *(const f32x4*)(part + 3*(size_t)N*HD + t4);
  float zz = zpart[h*N + i] + zpart[(4 + h)*N + i] + zpart[(8 + h)*N + i] + zpart[(12 + h)*N + i];
  f32x4 s = (a + bq + c + d) / zz;
  *(f32x4*)(out + t4) = s;
}

extern "C" void kernel_launch(void* const* d_in, const int* in_sizes, int n_in,
                              void* d_out, int out_size, void* d_ws, size_t ws_size,
                              hipStream_t stream) {
  const float* x   = (const float*)d_in[0];
  const int*   adj = (const int*)d_in[1];
  const float* W   = (const float*)d_in[2];
  const float* a_l = (const float*)d_in[3];
  const float* a_r = (const float*)d_in[4];
  float* out = (float*)d_out;

  char* ws = (char*)d_ws;
  __hip_bfloat16* Wt = (__hip_bfloat16*)ws;                     // 128 KB
  _Float16* ht   = (_Float16*)(ws + 131072);                    // 4 MB
  float*    El   = (float*)   (ws + 4325376);                   // 128 KB
  float*    El2  = (float*)   (ws + 4456448);                   // 128 KB
  _Float16* Erh  = (_Float16*)(ws + 4587520);                   // 64 KB
  _Float16* Er2h = (_Float16*)(ws + 4653056);                   // 64 KB
  float*    part = (float*)   (ws + 4718592);                   // 32 MB
  float*    zpart= (float*)   (ws + 38273024);                  // 512 KB
  unsigned* bits = (unsigned*)(ws + 38797312);                  // 8 MB bitmask

  k_wt  <<<dim3(16,16), dim3(16,16), 0, stream>>>(W, Wt);
  k_pack<<<N*N/4/256, 256, 0, stream>>>(adj, bits);
  k_h   <<<512, 256, 0, stream>>>(x, Wt, a_l, a_r, ht, El, El2, Erh, Er2h);
  k_attn<<<1024, 256, 0, stream>>>(bits, ht, El, El2, Erh, Er2h, part, zpart);
  k_out <<<N*HD/1024, 256, 0, stream>>>(part, zpart, out);
}

// Round 7
// 427.590 us; speedup vs baseline: 1.2318x; 1.2318x over previous
//
#include <hip/hip_runtime.h>
#include <hip/hip_bf16.h>
#include <hip/hip_fp16.h>

#define N 8192
#define FIN 256
#define HD 256
#define LEAKY 0.2f

typedef short sh8 __attribute__((ext_vector_type(8)));       // bf16x8 MFMA fragment
typedef _Float16 h8 __attribute__((ext_vector_type(8)));     // f16x8 MFMA fragment
typedef _Float16 h2 __attribute__((ext_vector_type(2)));
typedef float f32x4 __attribute__((ext_vector_type(4)));
typedef int   i32x4 __attribute__((ext_vector_type(4)));

__device__ __forceinline__ int pack2bf(float a, float b){
  __hip_bfloat162 t = __float22bfloat162_rn(make_float2(a, b));
  union { __hip_bfloat162 h; int i; } u;
  u.h = t;
  return u.i;
}

__device__ __forceinline__ h2 u2h2(unsigned u){ union{unsigned u; h2 h;} c; c.u=u; return c.h; }
__device__ __forceinline__ unsigned h22u(h2 h){ union{unsigned u; h2 h;} c; c.h=h; return c.u; }

// ---------------- K0: W (256x256 f32, [k][c]) -> Wt (bf16, [c][k]) ----------------
__global__ void k_wt(const float* __restrict__ W, __hip_bfloat16* __restrict__ Wt){
  __shared__ float t[16][17];
  int tx = threadIdx.x, ty = threadIdx.y;
  int bx = blockIdx.x*16, by = blockIdx.y*16;
  t[ty][tx] = W[(by+ty)*HD + (bx+tx)];
  __syncthreads();
  Wt[(bx+ty)*FIN + (by+tx)] = __float2bfloat16(t[tx][ty]);
}

// ---------------- K0b: adj (int32 {0,1}, 256 MB) -> interleaved bitmask (8 MB) -----
// word[i][c]: bit b (b<16) = keep(i, c*32+2b), bit 16+b = keep(i, c*32+2b+1).
// Identity diagonal folded in. Coalesced: one contiguous dwordx4 per thread, OR-
// combine across the 8-thread group via shfl_xor.
__global__ __launch_bounds__(256) void k_pack(const int* __restrict__ adj,
                                              unsigned* __restrict__ bits){
  const int g = blockIdx.x*256 + threadIdx.x;   // one dwordx4 chunk per thread
  const i32x4 a = *(const i32x4*)(adj + (size_t)g*4);
  const int sub = g & 7;                        // which 4-of-32 j this thread holds
  unsigned wpart = 0;
  #pragma unroll
  for (int e = 0; e < 4; ++e){
    const int jj = sub*4 + e;                   // j within the 32-chunk
    wpart |= ((unsigned)a[e] & 1u) << ((jj >> 1) + ((jj & 1) << 4));
  }
  wpart |= __shfl_xor(wpart, 1);
  wpart |= __shfl_xor(wpart, 2);
  wpart |= __shfl_xor(wpart, 4);
  if (sub == 0){
    const int t = g >> 3;                       // word index
    const int i = t >> 8;                       // row
    const int c = t & 255;                      // 32-j chunk
    if ((i >> 5) == c){                         // diagonal lands in this word
      const int k = i & 31;
      wpart |= 1u << ((k >> 1) + ((k & 1) << 4));
    }
    bits[t] = wpart;
  }
}

// ---------------- K1: h_t[c][n] (f16) + El/El2 fp32 + Erh/Er2h f16 ------------------
__global__ __launch_bounds__(256, 2) void k_h(
    const float* __restrict__ x, const __hip_bfloat16* __restrict__ Wt,
    const float* __restrict__ a_l, const float* __restrict__ a_r,
    _Float16* __restrict__ ht, float* __restrict__ El, float* __restrict__ El2,
    _Float16* __restrict__ Erh, _Float16* __restrict__ Er2h)
{
  const int lane = threadIdx.x & 63;
  const int w = threadIdx.x >> 6;      // c-group == head
  const int r0 = lane & 15, q = lane >> 4;
  const int c0 = w*64;
  const int n0 = blockIdx.x*16;

  f32x4 acc[4];
  #pragma unroll
  for (int m = 0; m < 4; ++m) acc[m] = (f32x4){0.f, 0.f, 0.f, 0.f};

  for (int kb = 0; kb < 8; ++kb){
    const int k = kb*32 + q*8;
    sh8 af[4];
    #pragma unroll
    for (int m = 0; m < 4; ++m)
      af[m] = *(const sh8*)(Wt + (c0 + m*16 + r0)*FIN + k);
    const float* xp = x + (n0 + r0)*FIN + k;
    f32x4 xl = *(const f32x4*)xp;
    f32x4 xh = *(const f32x4*)(xp + 4);
    union { sh8 s; int i[4]; } bx;
    bx.i[0] = pack2bf(xl[0], xl[1]);
    bx.i[1] = pack2bf(xl[2], xl[3]);
    bx.i[2] = pack2bf(xh[0], xh[1]);
    bx.i[3] = pack2bf(xh[2], xh[3]);
    #pragma unroll
    for (int m = 0; m < 4; ++m)
      acc[m] = __builtin_amdgcn_mfma_f32_16x16x32_bf16(af[m], bx.s, acc[m], 0, 0, 0);
  }

  float pl = 0.f, pr = 0.f;
  #pragma unroll
  for (int m = 0; m < 4; ++m){
    #pragma unroll
    for (int reg = 0; reg < 4; ++reg){
      const int c = c0 + m*16 + q*4 + reg;      // C row = q*4+reg
      const float v = acc[m][reg];
      ht[(size_t)c*N + (n0 + r0)] = (_Float16)v; // C col = r0
      pl += v*a_l[c];
      pr += v*a_r[c];
    }
  }
  pl += __shfl_xor(pl, 16); pl += __shfl_xor(pl, 32);
  pr += __shfl_xor(pr, 16); pr += __shfl_xor(pr, 32);
  if (lane < 16){
    const int n = n0 + r0;
    El  [w*N + n] = __expf(pl);
    El2 [w*N + n] = __expf(LEAKY*pl);
    Erh [w*N + n] = (_Float16)__expf(pr);
    Er2h[w*N + n] = (_Float16)__expf(LEAKY*pr);
  }
}

// ---------------- K2: fused bitmask + masked-softmax partials ----------------------
// R2-proven LDS-staged structure (R6 showed direct-global hf loads are latency-bound:
// a tile shared by all 4 waves must be staged via global_load_lds, which amortizes
// one fetch across waves and gives a full-tile prefetch distance).
// NEW: XCD-grouped decode b = i128*16 + h*4 + jq. Since 16 % 8 == 0, XCD = (h*4+jq)%8
// is CONSTANT per (h,jq) group -> each XCD's resident blocks cover exactly 2 (h,jq)
// groups (same jq): L2 working set = 2 ht slices (512 KB) + 1 bits quarter (1 MB)
// ~= 1.6 MB << 4 MB L2 (old decode spanned all 16 groups: ~12 MB, thrash).
// 4 waves, same head; wave w owns rows i128*128 + w*32 + {0,16} + r0.
// Bits prefetched one tile ahead; er slices staged once in LDS; ht tile dbuf 2x16KB.
__global__ __launch_bounds__(256, 4) void k_attn(
    const unsigned* __restrict__ bits, const _Float16* __restrict__ ht,
    const float* __restrict__ El, const float* __restrict__ El2,
    const _Float16* __restrict__ Erh, const _Float16* __restrict__ Er2h,
    float* __restrict__ part, float* __restrict__ zpart)
{
  __shared__ __align__(16) char smem[40960];    // 32 KB ht dbuf + 2x4 KB er slices
  const int b = blockIdx.x;
  const int i128 = b >> 4, h = (b >> 2) & 3, jq = b & 3;   // XCD-grouped decode
  const int tid = threadIdx.x;
  const int lane = tid & 63;
  const int w = tid >> 6;
  const int r0 = lane & 15, q = lane >> 4;
  const int ib = i128*128 + w*32;               // this wave's 32-row base
  const int jbase = jq * 2048;

  // ht staging (round-7 swizzle): feat f = w*16+(lane>>2); slot (lane&3) holds
  // global j-chunk (lane&3)^((lane>>3)&3). LDS dest = s*4096 + w*1024 + lane*16.
  const _Float16* gp = ht + (size_t)(h*64 + w*16 + (lane >> 2))*N
                          + jbase + (((lane & 3) ^ ((lane >> 3) & 3))*8);
  char* lb = smem + w*1024;
  // fragment read: (f = d*16+r0), slot q ^ ((r0>>1)&3) -> global chunk q
  const char* frp = smem + r0*64 + ((q ^ ((r0 >> 1) & 3)) << 4);

  // stage Erh/Er2h slices (4 KB each) -> LDS [32768..40960); wave w moves 1 KB each
  {
    const _Float16* s1 = Erh  + h*N + jbase + w*512 + lane*8;
    const _Float16* s2 = Er2h + h*N + jbase + w*512 + lane*8;
    __builtin_amdgcn_global_load_lds(
      (const __attribute__((address_space(1))) void*)s1,
      (__attribute__((address_space(3))) void*)(smem + 32768 + w*1024), 16, 0, 0);
    __builtin_amdgcn_global_load_lds(
      (const __attribute__((address_space(1))) void*)s2,
      (__attribute__((address_space(3))) void*)(smem + 36864 + w*1024), 16, 0, 0);
  }
  const char* erp1 = smem + 32768 + q*16;
  const char* erp2 = smem + 36864 + q*16;

  const float* el_ = El  + h*N + ib + r0;
  const float* el2_= El2 + h*N + ib + r0;
  h2 elh[2], el2h[2];
  #pragma unroll
  for (int m = 0; m < 2; ++m){
    _Float16 a = (_Float16)el_[m*16];
    _Float16 c = (_Float16)el2_[m*16];
    elh[m]  = (h2){a, a};
    el2h[m] = (h2){c, c};
  }

  // bitmask pointers: row (ib + m*16 + r0), word base jq*64; 4 words per t-tile
  const unsigned* bp0 = bits + (size_t)(ib + r0)*(N/32) + jq*64;
  const unsigned* bp1 = bp0 + 16*(N/32);
  const int qs = q*4;                            // pair p sits at bits (qs+p, 16+qs+p)

  union { h8 s; int i[4]; } onef;
  {
    int v = (r0 == 0) ? 0x3C003C00 : 0;          // f16 1.0 pair
    onef.i[0]=v; onef.i[1]=v; onef.i[2]=v; onef.i[3]=v;
  }

  f32x4 acc[2][4];
  f32x4 accz[2];
  #pragma unroll
  for (int m = 0; m < 2; ++m){
    accz[m] = (f32x4){0.f,0.f,0.f,0.f};
    #pragma unroll
    for (int d = 0; d < 4; ++d)
      acc[m][d] = (f32x4){0.f,0.f,0.f,0.f};
  }

#define STAGE(bufoff, t) do { \
    const _Float16* _g = gp + (t)*128; \
    _Pragma("unroll") \
    for (int _s = 0; _s < 4; ++_s) \
      __builtin_amdgcn_global_load_lds( \
        (const __attribute__((address_space(1))) void*)(_g + _s*32), \
        (__attribute__((address_space(3))) void*)(lb + (bufoff) + _s*4096), 16, 0, 0); \
  } while(0)

  i32x4 bcur[2], bnxt[2];                        // adjacency bits, current / next t
  bcur[0] = *(const i32x4*)(bp0);
  bcur[1] = *(const i32x4*)(bp1);
  STAGE(0, 0);
  __syncthreads();                               // tile 0 + er slices resident

  for (int t = 0; t < 16; ++t){
    const int bo = (t & 1) ? 16384 : 0;
    const int bn = bo ^ 16384;
    const int tn = (t + 1) & 15;                 // tail wrap harmless
    STAGE(bn, tn);                               // async: next ht tile -> other buffer
    bnxt[0] = *(const i32x4*)(bp0 + tn*4);       // next tile's adjacency bits
    bnxt[1] = *(const i32x4*)(bp1 + tn*4);

    #pragma unroll
    for (int ss = 0; ss < 4; ++ss){
      i32x4 er4  = *(const i32x4*)(erp1 + t*256 + ss*64);   // ds_read_b128 (broadcast)
      i32x4 er24 = *(const i32x4*)(erp2 + t*256 + ss*64);

      h8 hf[4];
      #pragma unroll
      for (int d = 0; d < 4; ++d)
        hf[d] = *(const h8*)(frp + bo + ss*4096 + d*1024);  // ds_read_b128

      #pragma unroll
      for (int m = 0; m < 2; ++m){
        const unsigned wq = ((unsigned)(m ? bcur[1][ss] : bcur[0][ss])) >> qs;
        unsigned fu[4];
        #pragma unroll
        for (int p = 0; p < 4; ++p){
          const unsigned t32 = (wq >> p) & 0x10001u;        // {even j, odd j} bits
          const unsigned msk = t32 * 0xFFFFu;               // -> f16 half masks
          h2 w2 = __builtin_elementwise_max(elh[m]  * u2h2((unsigned)er4[p]),
                                            el2h[m] * u2h2((unsigned)er24[p]));
          fu[p] = h22u(w2) & msk;
        }
        union { h8 s; unsigned u[4]; } fa;
        fa.u[0]=fu[0]; fa.u[1]=fu[1]; fa.u[2]=fu[2]; fa.u[3]=fu[3];
        __builtin_amdgcn_s_setprio(1);
        #pragma unroll
        for (int d = 0; d < 4; ++d)
          acc[m][d] = __builtin_amdgcn_mfma_f32_16x16x32_f16(fa.s, hf[d], acc[m][d], 0, 0, 0);
        accz[m] = __builtin_amdgcn_mfma_f32_16x16x32_f16(fa.s, onef.s, accz[m], 0, 0, 0);
        __builtin_amdgcn_s_setprio(0);
      }
    }

    bcur[0] = bnxt[0]; bcur[1] = bnxt[1];
    __syncthreads();                             // next ht tile staged; buf free
  }

  // z partials: col 0 of accz -> lanes with r0==0, row = q*4+reg
  if (r0 == 0){
    #pragma unroll
    for (int m = 0; m < 2; ++m)
      #pragma unroll
      for (int reg = 0; reg < 4; ++reg)
        zpart[(jq*4 + h)*N + ib + m*16 + q*4 + reg] = accz[m][reg];
  }

  // numerator partials: C layout col=r0, row=q*4+reg
  float* pp = part + (size_t)jq*N*HD + h*64 + r0;
  #pragma unroll
  for (int m = 0; m < 2; ++m)
    #pragma unroll
    for (int d = 0; d < 4; ++d)
      #pragma unroll
      for (int reg = 0; reg < 4; ++reg)
        pp[(size_t)(ib + m*16 + q*4 + reg)*HD + d*16] = acc[m][d][reg];
#undef STAGE
}

// ---------------- K3: combine 4 j-quarter partials, divide, write out --------------
__global__ void k_out(const float* __restrict__ part, const float* __restrict__ zpart,
                      float* __restrict__ out)
{
  const int t4 = (blockIdx.x*256 + threadIdx.x) * 4;   // 4 consecutive c (same head)
  const int i = t4 >> 8;
  const int h = (t4 & 255) >> 6;
  f32x4 a = *(const f32x4*)(part + t4);
  f32x4 bq = *(const f32x4*)(part + (size_t)N*HD + t4);
  f32x4 c = *(const f32x4*)(part + 2*(size_t)N*HD + t4);
  f32x4 d = *(const f32x4*)(part + 3*(size_t)N*HD + t4);
  float zz = zpart[h*N + i] + zpart[(4 + h)*N + i] + zpart[(8 + h)*N + i] + zpart[(12 + h)*N + i];
  f32x4 s = (a + bq + c + d) / zz;
  *(f32x4*)(out + t4) = s;
}

extern "C" void kernel_launch(void* const* d_in, const int* in_sizes, int n_in,
                              void* d_out, int out_size, void* d_ws, size_t ws_size,
                              hipStream_t stream) {
  const float* x   = (const float*)d_in[0];
  const int*   adj = (const int*)d_in[1];
  const float* W   = (const float*)d_in[2];
  const float* a_l = (const float*)d_in[3];
  const float* a_r = (const float*)d_in[4];
  float* out = (float*)d_out;

  char* ws = (char*)d_ws;
  __hip_bfloat16* Wt = (__hip_bfloat16*)ws;                     // 128 KB
  _Float16* ht   = (_Float16*)(ws + 131072);                    // 4 MB
  float*    El   = (float*)   (ws + 4325376);                   // 128 KB
  float*    El2  = (float*)   (ws + 4456448);                   // 128 KB
  _Float16* Erh  = (_Float16*)(ws + 4587520);                   // 64 KB
  _Float16* Er2h = (_Float16*)(ws + 4653056);                   // 64 KB
  float*    part = (float*)   (ws + 4718592);                   // 32 MB
  float*    zpart= (float*)   (ws + 38273024);                  // 512 KB
  unsigned* bits = (unsigned*)(ws + 38797312);                  // 8 MB bitmask

  k_wt  <<<dim3(16,16), dim3(16,16), 0, stream>>>(W, Wt);
  k_pack<<<N*N/4/256, 256, 0, stream>>>(adj, bits);
  k_h   <<<512, 256, 0, stream>>>(x, Wt, a_l, a_r, ht, El, El2, Erh, Er2h);
  k_attn<<<1024, 256, 0, stream>>>(bits, ht, El, El2, Erh, Er2h, part, zpart);
  k_out <<<N*HD/1024, 256, 0, stream>>>(part, zpart, out);
}

// Round 8
// 426.877 us; speedup vs baseline: 1.2338x; 1.0017x over previous
//
#include <hip/hip_runtime.h>
#include <hip/hip_bf16.h>
#include <hip/hip_fp16.h>

#define N 8192
#define FIN 256
#define HD 256
#define LEAKY 0.2f

typedef short sh8 __attribute__((ext_vector_type(8)));       // bf16x8 MFMA fragment
typedef _Float16 h8 __attribute__((ext_vector_type(8)));     // f16x8 MFMA fragment
typedef _Float16 h2 __attribute__((ext_vector_type(2)));
typedef float f32x4 __attribute__((ext_vector_type(4)));
typedef int   i32x4 __attribute__((ext_vector_type(4)));

__device__ __forceinline__ int pack2bf(float a, float b){
  __hip_bfloat162 t = __float22bfloat162_rn(make_float2(a, b));
  union { __hip_bfloat162 h; int i; } u;
  u.h = t;
  return u.i;
}

__device__ __forceinline__ h2 u2h2(unsigned u){ union{unsigned u; h2 h;} c; c.u=u; return c.h; }
__device__ __forceinline__ unsigned h22u(h2 h){ union{unsigned u; h2 h;} c; c.h=h; return c.u; }

// ---------------- K0: fused {W transpose} + {adj bit-pack} (independent work) -------
// blocks [0..256):    W (256x256 f32, [k][c]) -> Wt (bf16, [c][k])
// blocks [256..65792): adj (int32 {0,1}, 256 MB) -> interleaved bitmask (8 MB)
//   word[i][c]: bit b (b<16) = keep(i, c*32+2b), bit 16+b = keep(i, c*32+2b+1);
//   identity diagonal folded in. Coalesced dwordx4/thread + shfl_xor OR-combine.
// Fusion removes one graph-serialized dispatch; k_wt's 3 us hides under the pack
// stream (no data dependency between the two halves).
__global__ __launch_bounds__(256) void k_packwt(const int* __restrict__ adj,
                                                unsigned* __restrict__ bits,
                                                const float* __restrict__ W,
                                                __hip_bfloat16* __restrict__ Wt){
  if (blockIdx.x < 256){                        // ---- W transpose half ----
    __shared__ float t[16][17];
    const int tx = threadIdx.x & 15, ty = threadIdx.x >> 4;
    const int bx = (blockIdx.x & 15)*16, by = (blockIdx.x >> 4)*16;
    t[ty][tx] = W[(by+ty)*HD + (bx+tx)];
    __syncthreads();
    Wt[(bx+ty)*FIN + (by+tx)] = __float2bfloat16(t[tx][ty]);
    return;
  }
  const int g = (blockIdx.x - 256)*256 + threadIdx.x;   // one dwordx4 chunk per thread
  const i32x4 a = *(const i32x4*)(adj + (size_t)g*4);
  const int sub = g & 7;                        // which 4-of-32 j this thread holds
  unsigned wpart = 0;
  #pragma unroll
  for (int e = 0; e < 4; ++e){
    const int jj = sub*4 + e;                   // j within the 32-chunk
    wpart |= ((unsigned)a[e] & 1u) << ((jj >> 1) + ((jj & 1) << 4));
  }
  wpart |= __shfl_xor(wpart, 1);
  wpart |= __shfl_xor(wpart, 2);
  wpart |= __shfl_xor(wpart, 4);
  if (sub == 0){
    const int t = g >> 3;                       // word index
    const int i = t >> 8;                       // row
    const int c = t & 255;                      // 32-j chunk
    if ((i >> 5) == c){                         // diagonal lands in this word
      const int k = i & 31;
      wpart |= 1u << ((k >> 1) + ((k & 1) << 4));
    }
    bits[t] = wpart;
  }
}

// ---------------- K1: h_t[c][n] (f16) + El/El2 fp32 + Erh/Er2h f16 ------------------
__global__ __launch_bounds__(256, 2) void k_h(
    const float* __restrict__ x, const __hip_bfloat16* __restrict__ Wt,
    const float* __restrict__ a_l, const float* __restrict__ a_r,
    _Float16* __restrict__ ht, float* __restrict__ El, float* __restrict__ El2,
    _Float16* __restrict__ Erh, _Float16* __restrict__ Er2h)
{
  const int lane = threadIdx.x & 63;
  const int w = threadIdx.x >> 6;      // c-group == head
  const int r0 = lane & 15, q = lane >> 4;
  const int c0 = w*64;
  const int n0 = blockIdx.x*16;

  f32x4 acc[4];
  #pragma unroll
  for (int m = 0; m < 4; ++m) acc[m] = (f32x4){0.f, 0.f, 0.f, 0.f};

  for (int kb = 0; kb < 8; ++kb){
    const int k = kb*32 + q*8;
    sh8 af[4];
    #pragma unroll
    for (int m = 0; m < 4; ++m)
      af[m] = *(const sh8*)(Wt + (c0 + m*16 + r0)*FIN + k);
    const float* xp = x + (n0 + r0)*FIN + k;
    f32x4 xl = *(const f32x4*)xp;
    f32x4 xh = *(const f32x4*)(xp + 4);
    union { sh8 s; int i[4]; } bx;
    bx.i[0] = pack2bf(xl[0], xl[1]);
    bx.i[1] = pack2bf(xl[2], xl[3]);
    bx.i[2] = pack2bf(xh[0], xh[1]);
    bx.i[3] = pack2bf(xh[2], xh[3]);
    #pragma unroll
    for (int m = 0; m < 4; ++m)
      acc[m] = __builtin_amdgcn_mfma_f32_16x16x32_bf16(af[m], bx.s, acc[m], 0, 0, 0);
  }

  float pl = 0.f, pr = 0.f;
  #pragma unroll
  for (int m = 0; m < 4; ++m){
    #pragma unroll
    for (int reg = 0; reg < 4; ++reg){
      const int c = c0 + m*16 + q*4 + reg;      // C row = q*4+reg
      const float v = acc[m][reg];
      ht[(size_t)c*N + (n0 + r0)] = (_Float16)v; // C col = r0
      pl += v*a_l[c];
      pr += v*a_r[c];
    }
  }
  pl += __shfl_xor(pl, 16); pl += __shfl_xor(pl, 32);
  pr += __shfl_xor(pr, 16); pr += __shfl_xor(pr, 32);
  if (lane < 16){
    const int n = n0 + r0;
    El  [w*N + n] = __expf(pl);
    El2 [w*N + n] = __expf(LEAKY*pl);
    Erh [w*N + n] = (_Float16)__expf(pr);
    Er2h[w*N + n] = (_Float16)__expf(LEAKY*pr);
  }
}

// ---------------- K2: fused bitmask + masked-softmax partials ----------------------
// R2-proven LDS-staged structure + XCD-grouped decode b = i128*16 + h*4 + jq
// (XCD = (h*4+jq)%8 constant per group -> per-XCD L2 set ~1.6 MB << 4 MB).
// 4 waves, same head; wave w owns rows i128*128 + w*32 + {0,16} + r0.
// Bits prefetched one tile ahead; er slices staged once in LDS; ht tile dbuf 2x16KB.
__global__ __launch_bounds__(256, 4) void k_attn(
    const unsigned* __restrict__ bits, const _Float16* __restrict__ ht,
    const float* __restrict__ El, const float* __restrict__ El2,
    const _Float16* __restrict__ Erh, const _Float16* __restrict__ Er2h,
    float* __restrict__ part, float* __restrict__ zpart)
{
  __shared__ __align__(16) char smem[40960];    // 32 KB ht dbuf + 2x4 KB er slices
  const int b = blockIdx.x;
  const int i128 = b >> 4, h = (b >> 2) & 3, jq = b & 3;   // XCD-grouped decode
  const int tid = threadIdx.x;
  const int lane = tid & 63;
  const int w = tid >> 6;
  const int r0 = lane & 15, q = lane >> 4;
  const int ib = i128*128 + w*32;               // this wave's 32-row base
  const int jbase = jq * 2048;

  // ht staging (round-7 swizzle): feat f = w*16+(lane>>2); slot (lane&3) holds
  // global j-chunk (lane&3)^((lane>>3)&3). LDS dest = s*4096 + w*1024 + lane*16.
  const _Float16* gp = ht + (size_t)(h*64 + w*16 + (lane >> 2))*N
                          + jbase + (((lane & 3) ^ ((lane >> 3) & 3))*8);
  char* lb = smem + w*1024;
  // fragment read: (f = d*16+r0), slot q ^ ((r0>>1)&3) -> global chunk q
  const char* frp = smem + r0*64 + ((q ^ ((r0 >> 1) & 3)) << 4);

  // stage Erh/Er2h slices (4 KB each) -> LDS [32768..40960); wave w moves 1 KB each
  {
    const _Float16* s1 = Erh  + h*N + jbase + w*512 + lane*8;
    const _Float16* s2 = Er2h + h*N + jbase + w*512 + lane*8;
    __builtin_amdgcn_global_load_lds(
      (const __attribute__((address_space(1))) void*)s1,
      (__attribute__((address_space(3))) void*)(smem + 32768 + w*1024), 16, 0, 0);
    __builtin_amdgcn_global_load_lds(
      (const __attribute__((address_space(1))) void*)s2,
      (__attribute__((address_space(3))) void*)(smem + 36864 + w*1024), 16, 0, 0);
  }
  const char* erp1 = smem + 32768 + q*16;
  const char* erp2 = smem + 36864 + q*16;

  const float* el_ = El  + h*N + ib + r0;
  const float* el2_= El2 + h*N + ib + r0;
  h2 elh[2], el2h[2];
  #pragma unroll
  for (int m = 0; m < 2; ++m){
    _Float16 a = (_Float16)el_[m*16];
    _Float16 c = (_Float16)el2_[m*16];
    elh[m]  = (h2){a, a};
    el2h[m] = (h2){c, c};
  }

  // bitmask pointers: row (ib + m*16 + r0), word base jq*64; 4 words per t-tile
  const unsigned* bp0 = bits + (size_t)(ib + r0)*(N/32) + jq*64;
  const unsigned* bp1 = bp0 + 16*(N/32);
  const int qs = q*4;                            // pair p sits at bits (qs+p, 16+qs+p)

  union { h8 s; int i[4]; } onef;
  {
    int v = (r0 == 0) ? 0x3C003C00 : 0;          // f16 1.0 pair
    onef.i[0]=v; onef.i[1]=v; onef.i[2]=v; onef.i[3]=v;
  }

  f32x4 acc[2][4];
  f32x4 accz[2];
  #pragma unroll
  for (int m = 0; m < 2; ++m){
    accz[m] = (f32x4){0.f,0.f,0.f,0.f};
    #pragma unroll
    for (int d = 0; d < 4; ++d)
      acc[m][d] = (f32x4){0.f,0.f,0.f,0.f};
  }

#define STAGE(bufoff, t) do { \
    const _Float16* _g = gp + (t)*128; \
    _Pragma("unroll") \
    for (int _s = 0; _s < 4; ++_s) \
      __builtin_amdgcn_global_load_lds( \
        (const __attribute__((address_space(1))) void*)(_g + _s*32), \
        (__attribute__((address_space(3))) void*)(lb + (bufoff) + _s*4096), 16, 0, 0); \
  } while(0)

  i32x4 bcur[2], bnxt[2];                        // adjacency bits, current / next t
  bcur[0] = *(const i32x4*)(bp0);
  bcur[1] = *(const i32x4*)(bp1);
  STAGE(0, 0);
  __syncthreads();                               // tile 0 + er slices resident

  for (int t = 0; t < 16; ++t){
    const int bo = (t & 1) ? 16384 : 0;
    const int bn = bo ^ 16384;
    const int tn = (t + 1) & 15;                 // tail wrap harmless
    STAGE(bn, tn);                               // async: next ht tile -> other buffer
    bnxt[0] = *(const i32x4*)(bp0 + tn*4);       // next tile's adjacency bits
    bnxt[1] = *(const i32x4*)(bp1 + tn*4);

    #pragma unroll
    for (int ss = 0; ss < 4; ++ss){
      i32x4 er4  = *(const i32x4*)(erp1 + t*256 + ss*64);   // ds_read_b128 (broadcast)
      i32x4 er24 = *(const i32x4*)(erp2 + t*256 + ss*64);

      h8 hf[4];
      #pragma unroll
      for (int d = 0; d < 4; ++d)
        hf[d] = *(const h8*)(frp + bo + ss*4096 + d*1024);  // ds_read_b128

      #pragma unroll
      for (int m = 0; m < 2; ++m){
        const unsigned wq = ((unsigned)(m ? bcur[1][ss] : bcur[0][ss])) >> qs;
        unsigned fu[4];
        #pragma unroll
        for (int p = 0; p < 4; ++p){
          const unsigned t32 = (wq >> p) & 0x10001u;        // {even j, odd j} bits
          const unsigned msk = t32 * 0xFFFFu;               // -> f16 half masks
          h2 w2 = __builtin_elementwise_max(elh[m]  * u2h2((unsigned)er4[p]),
                                            el2h[m] * u2h2((unsigned)er24[p]));
          fu[p] = h22u(w2) & msk;
        }
        union { h8 s; unsigned u[4]; } fa;
        fa.u[0]=fu[0]; fa.u[1]=fu[1]; fa.u[2]=fu[2]; fa.u[3]=fu[3];
        __builtin_amdgcn_s_setprio(1);
        #pragma unroll
        for (int d = 0; d < 4; ++d)
          acc[m][d] = __builtin_amdgcn_mfma_f32_16x16x32_f16(fa.s, hf[d], acc[m][d], 0, 0, 0);
        accz[m] = __builtin_amdgcn_mfma_f32_16x16x32_f16(fa.s, onef.s, accz[m], 0, 0, 0);
        __builtin_amdgcn_s_setprio(0);
      }
    }

    bcur[0] = bnxt[0]; bcur[1] = bnxt[1];
    __syncthreads();                             // next ht tile staged; buf free
  }

  // z partials: col 0 of accz -> lanes with r0==0, row = q*4+reg
  if (r0 == 0){
    #pragma unroll
    for (int m = 0; m < 2; ++m)
      #pragma unroll
      for (int reg = 0; reg < 4; ++reg)
        zpart[(jq*4 + h)*N + ib + m*16 + q*4 + reg] = accz[m][reg];
  }

  // numerator partials: C layout col=r0, row=q*4+reg
  float* pp = part + (size_t)jq*N*HD + h*64 + r0;
  #pragma unroll
  for (int m = 0; m < 2; ++m)
    #pragma unroll
    for (int d = 0; d < 4; ++d)
      #pragma unroll
      for (int reg = 0; reg < 4; ++reg)
        pp[(size_t)(ib + m*16 + q*4 + reg)*HD + d*16] = acc[m][d][reg];
#undef STAGE
}

// ---------------- K3: combine 4 j-quarter partials, divide, write out --------------
__global__ void k_out(const float* __restrict__ part, const float* __restrict__ zpart,
                      float* __restrict__ out)
{
  const int t4 = (blockIdx.x*256 + threadIdx.x) * 4;   // 4 consecutive c (same head)
  const int i = t4 >> 8;
  const int h = (t4 & 255) >> 6;
  f32x4 a = *(const f32x4*)(part + t4);
  f32x4 bq = *(const f32x4*)(part + (size_t)N*HD + t4);
  f32x4 c = *(const f32x4*)(part + 2*(size_t)N*HD + t4);
  f32x4 d = *(const f32x4*)(part + 3*(size_t)N*HD + t4);
  float zz = zpart[h*N + i] + zpart[(4 + h)*N + i] + zpart[(8 + h)*N + i] + zpart[(12 + h)*N + i];
  f32x4 s = (a + bq + c + d) / zz;
  *(f32x4*)(out + t4) = s;
}

extern "C" void kernel_launch(void* const* d_in, const int* in_sizes, int n_in,
                              void* d_out, int out_size, void* d_ws, size_t ws_size,
                              hipStream_t stream) {
  const float* x   = (const float*)d_in[0];
  const int*   adj = (const int*)d_in[1];
  const float* W   = (const float*)d_in[2];
  const float* a_l = (const float*)d_in[3];
  const float* a_r = (const float*)d_in[4];
  float* out = (float*)d_out;

  char* ws = (char*)d_ws;
  __hip_bfloat16* Wt = (__hip_bfloat16*)ws;                     // 128 KB
  _Float16* ht   = (_Float16*)(ws + 131072);                    // 4 MB
  float*    El   = (float*)   (ws + 4325376);                   // 128 KB
  float*    El2  = (float*)   (ws + 4456448);                   // 128 KB
  _Float16* Erh  = (_Float16*)(ws + 4587520);                   // 64 KB
  _Float16* Er2h = (_Float16*)(ws + 4653056);                   // 64 KB
  float*    part = (float*)   (ws + 4718592);                   // 32 MB
  float*    zpart= (float*)   (ws + 38273024);                  // 512 KB
  unsigned* bits = (unsigned*)(ws + 38797312);                  // 8 MB bitmask

  k_packwt<<<N*N/4/256 + 256, 256, 0, stream>>>(adj, bits, W, Wt);
  k_h   <<<512, 256, 0, stream>>>(x, Wt, a_l, a_r, ht, El, El2, Erh, Er2h);
  k_attn<<<1024, 256, 0, stream>>>(bits, ht, El, El2, Erh, Er2h, part, zpart);
  k_out <<<N*HD/1024, 256, 0, stream>>>(part, zpart, out);
}

// Round 9
// 420.825 us; speedup vs baseline: 1.2516x; 1.0144x over previous
//
#include <hip/hip_runtime.h>
#include <hip/hip_bf16.h>
#include <hip/hip_fp16.h>

#define N 8192
#define FIN 256
#define HD 256
#define LEAKY 0.2f

typedef short sh8 __attribute__((ext_vector_type(8)));       // bf16x8 MFMA fragment
typedef _Float16 h8 __attribute__((ext_vector_type(8)));     // f16x8 MFMA fragment
typedef _Float16 h2 __attribute__((ext_vector_type(2)));
typedef float f32x4 __attribute__((ext_vector_type(4)));
typedef int   i32x4 __attribute__((ext_vector_type(4)));

__device__ __forceinline__ int pack2bf(float a, float b){
  __hip_bfloat162 t = __float22bfloat162_rn(make_float2(a, b));
  union { __hip_bfloat162 h; int i; } u;
  u.h = t;
  return u.i;
}

__device__ __forceinline__ h2 u2h2(unsigned u){ union{unsigned u; h2 h;} c; c.u=u; return c.h; }
__device__ __forceinline__ unsigned h22u(h2 h){ union{unsigned u; h2 h;} c; c.h=h; return c.u; }

// ---------------- K0: W (256x256 f32, [k][c]) -> Wt (bf16, [c][k]) ----------------
__global__ void k_wt(const float* __restrict__ W, __hip_bfloat16* __restrict__ Wt){
  __shared__ float t[16][17];
  int tx = threadIdx.x, ty = threadIdx.y;
  int bx = blockIdx.x*16, by = blockIdx.y*16;
  t[ty][tx] = W[(by+ty)*HD + (bx+tx)];
  __syncthreads();
  Wt[(bx+ty)*FIN + (by+tx)] = __float2bfloat16(t[tx][ty]);
}

// ---------------- K1: fused {h-projection} + {adj bit-pack} (independent work) ------
// blocks [0..512):      h_t[c][n] (f16) + El/El2 fp32 + Erh/Er2h f16  (needs Wt, x)
// blocks [512..66048):  adj (int32 {0,1}, 256 MB) -> interleaved bitmask (8 MB)
//   word[i][c]: bit b (b<16) = keep(i, c*32+2b), bit 16+b = keep(i, c*32+2b+1);
//   identity diagonal folded in. Coalesced dwordx4/thread + shfl_xor OR-combine.
// The two halves touch disjoint data (x,Wt vs adj) -> k_h's ~20 us hides entirely
// under the pack HBM stream. k_h blocks are dispatched first so they start at once.
__global__ __launch_bounds__(256, 2) void k_hpack(
    const float* __restrict__ x, const __hip_bfloat16* __restrict__ Wt,
    const float* __restrict__ a_l, const float* __restrict__ a_r,
    _Float16* __restrict__ ht, float* __restrict__ El, float* __restrict__ El2,
    _Float16* __restrict__ Erh, _Float16* __restrict__ Er2h,
    const int* __restrict__ adj, unsigned* __restrict__ bits)
{
  if (blockIdx.x >= 512){                       // ---- adj bit-pack half ----
    const int g = (blockIdx.x - 512)*256 + threadIdx.x;  // one dwordx4 per thread
    const i32x4 a = *(const i32x4*)(adj + (size_t)g*4);
    const int sub = g & 7;                      // which 4-of-32 j this thread holds
    unsigned wpart = 0;
    #pragma unroll
    for (int e = 0; e < 4; ++e){
      const int jj = sub*4 + e;                 // j within the 32-chunk
      wpart |= ((unsigned)a[e] & 1u) << ((jj >> 1) + ((jj & 1) << 4));
    }
    wpart |= __shfl_xor(wpart, 1);
    wpart |= __shfl_xor(wpart, 2);
    wpart |= __shfl_xor(wpart, 4);
    if (sub == 0){
      const int t = g >> 3;                     // word index
      const int i = t >> 8;                     // row
      const int c = t & 255;                    // 32-j chunk
      if ((i >> 5) == c){                       // diagonal lands in this word
        const int k = i & 31;
        wpart |= 1u << ((k >> 1) + ((k & 1) << 4));
      }
      bits[t] = wpart;
    }
    return;
  }

  // ---- h-projection half (identical to previous k_h) ----
  const int lane = threadIdx.x & 63;
  const int w = threadIdx.x >> 6;      // c-group == head
  const int r0 = lane & 15, q = lane >> 4;
  const int c0 = w*64;
  const int n0 = blockIdx.x*16;

  f32x4 acc[4];
  #pragma unroll
  for (int m = 0; m < 4; ++m) acc[m] = (f32x4){0.f, 0.f, 0.f, 0.f};

  for (int kb = 0; kb < 8; ++kb){
    const int k = kb*32 + q*8;
    sh8 af[4];
    #pragma unroll
    for (int m = 0; m < 4; ++m)
      af[m] = *(const sh8*)(Wt + (c0 + m*16 + r0)*FIN + k);
    const float* xp = x + (n0 + r0)*FIN + k;
    f32x4 xl = *(const f32x4*)xp;
    f32x4 xh = *(const f32x4*)(xp + 4);
    union { sh8 s; int i[4]; } bx;
    bx.i[0] = pack2bf(xl[0], xl[1]);
    bx.i[1] = pack2bf(xl[2], xl[3]);
    bx.i[2] = pack2bf(xh[0], xh[1]);
    bx.i[3] = pack2bf(xh[2], xh[3]);
    #pragma unroll
    for (int m = 0; m < 4; ++m)
      acc[m] = __builtin_amdgcn_mfma_f32_16x16x32_bf16(af[m], bx.s, acc[m], 0, 0, 0);
  }

  float pl = 0.f, pr = 0.f;
  #pragma unroll
  for (int m = 0; m < 4; ++m){
    #pragma unroll
    for (int reg = 0; reg < 4; ++reg){
      const int c = c0 + m*16 + q*4 + reg;      // C row = q*4+reg
      const float v = acc[m][reg];
      ht[(size_t)c*N + (n0 + r0)] = (_Float16)v; // C col = r0
      pl += v*a_l[c];
      pr += v*a_r[c];
    }
  }
  pl += __shfl_xor(pl, 16); pl += __shfl_xor(pl, 32);
  pr += __shfl_xor(pr, 16); pr += __shfl_xor(pr, 32);
  if (lane < 16){
    const int n = n0 + r0;
    El  [w*N + n] = __expf(pl);
    El2 [w*N + n] = __expf(LEAKY*pl);
    Erh [w*N + n] = (_Float16)__expf(pr);
    Er2h[w*N + n] = (_Float16)__expf(LEAKY*pr);
  }
}

// ---------------- K2: fused bitmask + masked-softmax partials ----------------------
// R2-proven LDS-staged structure + XCD-grouped decode b = i128*16 + h*4 + jq
// (XCD = (h*4+jq)%8 constant per group -> per-XCD L2 set ~1.6 MB << 4 MB).
// 4 waves, same head; wave w owns rows i128*128 + w*32 + {0,16} + r0.
// Bits prefetched one tile ahead; er slices staged once in LDS; ht tile dbuf 2x16KB.
__global__ __launch_bounds__(256, 4) void k_attn(
    const unsigned* __restrict__ bits, const _Float16* __restrict__ ht,
    const float* __restrict__ El, const float* __restrict__ El2,
    const _Float16* __restrict__ Erh, const _Float16* __restrict__ Er2h,
    float* __restrict__ part, float* __restrict__ zpart)
{
  __shared__ __align__(16) char smem[40960];    // 32 KB ht dbuf + 2x4 KB er slices
  const int b = blockIdx.x;
  const int i128 = b >> 4, h = (b >> 2) & 3, jq = b & 3;   // XCD-grouped decode
  const int tid = threadIdx.x;
  const int lane = tid & 63;
  const int w = tid >> 6;
  const int r0 = lane & 15, q = lane >> 4;
  const int ib = i128*128 + w*32;               // this wave's 32-row base
  const int jbase = jq * 2048;

  // ht staging (round-7 swizzle): feat f = w*16+(lane>>2); slot (lane&3) holds
  // global j-chunk (lane&3)^((lane>>3)&3). LDS dest = s*4096 + w*1024 + lane*16.
  const _Float16* gp = ht + (size_t)(h*64 + w*16 + (lane >> 2))*N
                          + jbase + (((lane & 3) ^ ((lane >> 3) & 3))*8);
  char* lb = smem + w*1024;
  // fragment read: (f = d*16+r0), slot q ^ ((r0>>1)&3) -> global chunk q
  const char* frp = smem + r0*64 + ((q ^ ((r0 >> 1) & 3)) << 4);

  // stage Erh/Er2h slices (4 KB each) -> LDS [32768..40960); wave w moves 1 KB each
  {
    const _Float16* s1 = Erh  + h*N + jbase + w*512 + lane*8;
    const _Float16* s2 = Er2h + h*N + jbase + w*512 + lane*8;
    __builtin_amdgcn_global_load_lds(
      (const __attribute__((address_space(1))) void*)s1,
      (__attribute__((address_space(3))) void*)(smem + 32768 + w*1024), 16, 0, 0);
    __builtin_amdgcn_global_load_lds(
      (const __attribute__((address_space(1))) void*)s2,
      (__attribute__((address_space(3))) void*)(smem + 36864 + w*1024), 16, 0, 0);
  }
  const char* erp1 = smem + 32768 + q*16;
  const char* erp2 = smem + 36864 + q*16;

  const float* el_ = El  + h*N + ib + r0;
  const float* el2_= El2 + h*N + ib + r0;
  h2 elh[2], el2h[2];
  #pragma unroll
  for (int m = 0; m < 2; ++m){
    _Float16 a = (_Float16)el_[m*16];
    _Float16 c = (_Float16)el2_[m*16];
    elh[m]  = (h2){a, a};
    el2h[m] = (h2){c, c};
  }

  // bitmask pointers: row (ib + m*16 + r0), word base jq*64; 4 words per t-tile
  const unsigned* bp0 = bits + (size_t)(ib + r0)*(N/32) + jq*64;
  const unsigned* bp1 = bp0 + 16*(N/32);
  const int qs = q*4;                            // pair p sits at bits (qs+p, 16+qs+p)

  union { h8 s; int i[4]; } onef;
  {
    int v = (r0 == 0) ? 0x3C003C00 : 0;          // f16 1.0 pair
    onef.i[0]=v; onef.i[1]=v; onef.i[2]=v; onef.i[3]=v;
  }

  f32x4 acc[2][4];
  f32x4 accz[2];
  #pragma unroll
  for (int m = 0; m < 2; ++m){
    accz[m] = (f32x4){0.f,0.f,0.f,0.f};
    #pragma unroll
    for (int d = 0; d < 4; ++d)
      acc[m][d] = (f32x4){0.f,0.f,0.f,0.f};
  }

#define STAGE(bufoff, t) do { \
    const _Float16* _g = gp + (t)*128; \
    _Pragma("unroll") \
    for (int _s = 0; _s < 4; ++_s) \
      __builtin_amdgcn_global_load_lds( \
        (const __attribute__((address_space(1))) void*)(_g + _s*32), \
        (__attribute__((address_space(3))) void*)(lb + (bufoff) + _s*4096), 16, 0, 0); \
  } while(0)

  i32x4 bcur[2], bnxt[2];                        // adjacency bits, current / next t
  bcur[0] = *(const i32x4*)(bp0);
  bcur[1] = *(const i32x4*)(bp1);
  STAGE(0, 0);
  __syncthreads();                               // tile 0 + er slices resident

  for (int t = 0; t < 16; ++t){
    const int bo = (t & 1) ? 16384 : 0;
    const int bn = bo ^ 16384;
    const int tn = (t + 1) & 15;                 // tail wrap harmless
    STAGE(bn, tn);                               // async: next ht tile -> other buffer
    bnxt[0] = *(const i32x4*)(bp0 + tn*4);       // next tile's adjacency bits
    bnxt[1] = *(const i32x4*)(bp1 + tn*4);

    #pragma unroll
    for (int ss = 0; ss < 4; ++ss){
      i32x4 er4  = *(const i32x4*)(erp1 + t*256 + ss*64);   // ds_read_b128 (broadcast)
      i32x4 er24 = *(const i32x4*)(erp2 + t*256 + ss*64);

      h8 hf[4];
      #pragma unroll
      for (int d = 0; d < 4; ++d)
        hf[d] = *(const h8*)(frp + bo + ss*4096 + d*1024);  // ds_read_b128

      #pragma unroll
      for (int m = 0; m < 2; ++m){
        const unsigned wq = ((unsigned)(m ? bcur[1][ss] : bcur[0][ss])) >> qs;
        unsigned fu[4];
        #pragma unroll
        for (int p = 0; p < 4; ++p){
          const unsigned t32 = (wq >> p) & 0x10001u;        // {even j, odd j} bits
          const unsigned msk = t32 * 0xFFFFu;               // -> f16 half masks
          h2 w2 = __builtin_elementwise_max(elh[m]  * u2h2((unsigned)er4[p]),
                                            el2h[m] * u2h2((unsigned)er24[p]));
          fu[p] = h22u(w2) & msk;
        }
        union { h8 s; unsigned u[4]; } fa;
        fa.u[0]=fu[0]; fa.u[1]=fu[1]; fa.u[2]=fu[2]; fa.u[3]=fu[3];
        __builtin_amdgcn_s_setprio(1);
        #pragma unroll
        for (int d = 0; d < 4; ++d)
          acc[m][d] = __builtin_amdgcn_mfma_f32_16x16x32_f16(fa.s, hf[d], acc[m][d], 0, 0, 0);
        accz[m] = __builtin_amdgcn_mfma_f32_16x16x32_f16(fa.s, onef.s, accz[m], 0, 0, 0);
        __builtin_amdgcn_s_setprio(0);
      }
    }

    bcur[0] = bnxt[0]; bcur[1] = bnxt[1];
    __syncthreads();                             // next ht tile staged; buf free
  }

  // z partials: col 0 of accz -> lanes with r0==0, row = q*4+reg
  if (r0 == 0){
    #pragma unroll
    for (int m = 0; m < 2; ++m)
      #pragma unroll
      for (int reg = 0; reg < 4; ++reg)
        zpart[(jq*4 + h)*N + ib + m*16 + q*4 + reg] = accz[m][reg];
  }

  // numerator partials: C layout col=r0, row=q*4+reg
  float* pp = part + (size_t)jq*N*HD + h*64 + r0;
  #pragma unroll
  for (int m = 0; m < 2; ++m)
    #pragma unroll
    for (int d = 0; d < 4; ++d)
      #pragma unroll
      for (int reg = 0; reg < 4; ++reg)
        pp[(size_t)(ib + m*16 + q*4 + reg)*HD + d*16] = acc[m][d][reg];
#undef STAGE
}

// ---------------- K3: combine 4 j-quarter partials, divide, write out --------------
__global__ void k_out(const float* __restrict__ part, const float* __restrict__ zpart,
                      float* __restrict__ out)
{
  const int t4 = (blockIdx.x*256 + threadIdx.x) * 4;   // 4 consecutive c (same head)
  const int i = t4 >> 8;
  const int h = (t4 & 255) >> 6;
  f32x4 a = *(const f32x4*)(part + t4);
  f32x4 bq = *(const f32x4*)(part + (size_t)N*HD + t4);
  f32x4 c = *(const f32x4*)(part + 2*(size_t)N*HD + t4);
  f32x4 d = *(const f32x4*)(part + 3*(size_t)N*HD + t4);
  float zz = zpart[h*N + i] + zpart[(4 + h)*N + i] + zpart[(8 + h)*N + i] + zpart[(12 + h)*N + i];
  f32x4 s = (a + bq + c + d) / zz;
  *(f32x4*)(out + t4) = s;
}

extern "C" void kernel_launch(void* const* d_in, const int* in_sizes, int n_in,
                              void* d_out, int out_size, void* d_ws, size_t ws_size,
                              hipStream_t stream) {
  const float* x   = (const float*)d_in[0];
  const int*   adj = (const int*)d_in[1];
  const float* W   = (const float*)d_in[2];
  const float* a_l = (const float*)d_in[3];
  const float* a_r = (const float*)d_in[4];
  float* out = (float*)d_out;

  char* ws = (char*)d_ws;
  __hip_bfloat16* Wt = (__hip_bfloat16*)ws;                     // 128 KB
  _Float16* ht   = (_Float16*)(ws + 131072);                    // 4 MB
  float*    El   = (float*)   (ws + 4325376);                   // 128 KB
  float*    El2  = (float*)   (ws + 4456448);                   // 128 KB
  _Float16* Erh  = (_Float16*)(ws + 4587520);                   // 64 KB
  _Float16* Er2h = (_Float16*)(ws + 4653056);                   // 64 KB
  float*    part = (float*)   (ws + 4718592);                   // 32 MB
  float*    zpart= (float*)   (ws + 38273024);                  // 512 KB
  unsigned* bits = (unsigned*)(ws + 38797312);                  // 8 MB bitmask

  k_wt   <<<dim3(16,16), dim3(16,16), 0, stream>>>(W, Wt);
  k_hpack<<<512 + N*N/4/256, 256, 0, stream>>>(x, Wt, a_l, a_r, ht, El, El2, Erh, Er2h, adj, bits);
  k_attn <<<1024, 256, 0, stream>>>(bits, ht, El, El2, Erh, Er2h, part, zpart);
  k_out  <<<N*HD/1024, 256, 0, stream>>>(part, zpart, out);
}